// Round 6
// baseline (214.074 us; speedup 1.0000x reference)
//
#include <hip/hip_runtime.h>
#include <hip/hip_bf16.h>
#include <cstdint>
#include <cstddef>

// Problem constants: T=1024, H=1024, I=512, E=16, K=4
#define T_TOK 1024
#define HDIM  1024
#define IDIM  512
#define NEXP  16
#define TOPK  4
#define CAP   1024   // per-expert entry capacity
#define MAXTILES 48  // max sum of ceil(cnt_e/128): (4096 + 16*127)/128 < 48

typedef __bf16 bf16;
typedef __attribute__((ext_vector_type(8))) __bf16 bf16x8;
typedef __attribute__((ext_vector_type(4))) __bf16 bf16x4;
typedef __attribute__((ext_vector_type(4))) float f32x4;

// counted waits + raw barriers (T4): A-prefetch and B-reg loads survive barriers.
#define WAIT_VM12  asm volatile("s_waitcnt vmcnt(12)" ::: "memory")
#define WAIT_VM0   asm volatile("s_waitcnt vmcnt(0)" ::: "memory")
#define BAR() do { asm volatile("" ::: "memory"); __builtin_amdgcn_s_barrier(); \
                   asm volatile("" ::: "memory"); } while (0)

__device__ __forceinline__ void lds_load16(void* lds_dst, const void* g_src) {
  __builtin_amdgcn_global_load_lds(
      (__attribute__((address_space(1))) unsigned int*)(void*)(g_src),
      (__attribute__((address_space(3))) unsigned int*)(lds_dst),
      16, 0, 0);
}

__device__ __forceinline__ bf16x4 cvt4(float4 a) {
  bf16x4 o;
  o[0] = (bf16)a.x; o[1] = (bf16)a.y; o[2] = (bf16)a.z; o[3] = (bf16)a.w;
  return o;
}

__device__ __forceinline__ bf16x8 pack8(float4 a, float4 b) {
  bf16x8 o;
  o[0] = (bf16)a.x; o[1] = (bf16)a.y; o[2] = (bf16)a.z; o[3] = (bf16)a.w;
  o[4] = (bf16)b.x; o[5] = (bf16)b.y; o[6] = (bf16)b.z; o[7] = (bf16)b.w;
  return o;
}

// work assignment: flat tile index -> (expert, m-tile) by scanning cntpad.
// Returns false if idx beyond total tiles (block exits before any barrier).
__device__ __forceinline__ bool tile_lookup(const int* cntpad, int idx,
                                            int& e_out, int& mt_out) {
  int rem = idx;
  for (int e = 0; e < NEXP; ++e) {
    int nt = cntpad[e] >> 7;
    if (rem < nt) { e_out = e; mt_out = rem; return true; }
    rem -= nt;
  }
  return false;
}

// ---------------- fused prep: cvt hid->bf16, zero out, routing ----------------

#define CVT_BLOCKS (T_TOK * HDIM / 4 / 256)   // 1024

__global__ void prep_kernel(const float* __restrict__ hid_f, bf16* __restrict__ hid_b,
                            const int* __restrict__ idx, const float* __restrict__ w,
                            int* __restrict__ etk, float* __restrict__ ew,
                            int* __restrict__ cntpad, float* __restrict__ out) {
  __shared__ int cnt;
  const int b = blockIdx.x;
  const int tid = threadIdx.x;
  if (b < CVT_BLOCKS) {
    int i = b * 256 + tid;
    float4 v = ((const float4*)hid_f)[i];
    ((bf16x4*)hid_b)[i] = cvt4(v);
    ((float4*)out)[i] = make_float4(0.f, 0.f, 0.f, 0.f);
    if (b == 0)  // zero pad row T
      ((bf16x4*)(hid_b + (size_t)T_TOK * HDIM))[tid] = cvt4(make_float4(0.f, 0.f, 0.f, 0.f));
    return;
  }
  const int e = b - CVT_BLOCKS;
  if (tid == 0) cnt = 0;
  __syncthreads();
  for (int j = tid; j < T_TOK * TOPK; j += blockDim.x) {
    if (idx[j] == e) {
      int slot = atomicAdd(&cnt, 1);
      if (slot < CAP) { etk[e * CAP + slot] = j; ew[e * CAP + slot] = w[j]; }
    }
  }
  __syncthreads();
  int c = cnt < CAP ? cnt : CAP;
  int p = (c + 127) & ~127;            // pad to M-tile (128)
  for (int j = c + tid; j < p; j += blockDim.x) {
    etk[e * CAP + j] = (T_TOK << 2);   // points at zeroed row T
    ew[e * CAP + j] = 0.f;
  }
  if (tid == 0) cntpad[e] = p;
}

// ---------------- GEMM1: hsc[entry, i] = silu(g)*u*wgt ----------------
// v6: counted-vmcnt pipeline. LDS holds ONLY A (double-buffered, global_load_lds,
// each wave's own vmcnt gates its stage before s_barrier -- m201-verified pattern).
// B fragments load DIRECTLY global->reg per lane (row n0+wi+lcol, k-slice
// lquad*8, mirroring the A-fragment layout), cvt in-reg. No ds_write, no
// cross-wave LDS WAR anywhere. ONE raw barrier per K-step; 12 VMEM/iter;
// vmcnt(12) retires all of iter k-1 (robust for any emission >= 12).
// One (e,mt) tile per block via cntpad scan -> perfect balance, no idle blocks.
// Tile M=128 x 32 i-ch (G+U), BK=64, 16 steps, 4 waves 2m x 2i, 16 MFMA/wave/step.
// LDS 32 KB.

__global__ __launch_bounds__(256, 3) void gemm1_kernel(
    const bf16* __restrict__ hid,    // [(T+1),H] bf16, row T zeroed
    const float* __restrict__ gup,   // [E,2I,H] fp32
    const int* __restrict__ etk, const float* __restrict__ ew,
    const int* __restrict__ cntpad,
    bf16* __restrict__ hsc) {        // [E*CAP, I] bf16
  __shared__ __align__(16) bf16 As[2][128 * 64];  // 32 KB
  int e, mt;
  if (!tile_lookup(cntpad, blockIdx.y, e, mt)) return;  // uniform exit, pre-barrier
  const int n0 = blockIdx.x * 32;
  const int ebase = e * CAP;
  const int tid = threadIdx.x, lane = tid & 63, wid = tid >> 6;
  const int wm = (wid >> 1) * 64, wi = (wid & 1) * 16;
  const int lcol = lane & 15, lquad = lane >> 4;
  const int l7 = lcol & 7;
  const int srow = tid >> 3;
  const int swz = ((tid & 7) ^ (srow & 7)) * 8;
  const int mrow = ebase + mt * 128;
  const bf16* gA[4];
#pragma unroll
  for (int q = 0; q < 4; ++q)
    gA[q] = hid + (size_t)(etk[mrow + srow + 32 * q] >> 2) * HDIM + swz;
  // direct B fragment pointers: lane covers G row (n0+wi+lcol), U row +IDIM;
  // k-offset per step: k*64 + ks*32 + lquad*8 (+0/+4 for the two float4).
  const float* gBg = gup + (size_t)e * (2 * IDIM) * HDIM
                   + (size_t)(n0 + wi + lcol) * HDIM + lquad * 8;
  const float* gBu = gBg + (size_t)IDIM * HDIM;

  f32x4 aG[4], aU[4];
#pragma unroll
  for (int mf = 0; mf < 4; ++mf) {
    aG[mf] = f32x4{0.f, 0.f, 0.f, 0.f};
    aU[mf] = f32x4{0.f, 0.f, 0.f, 0.f};
  }
  float4 bgv[2][2], buv[2][2];
  // prologue: A(0) -> As[0] (4 VMEM), B(0) -> regs (8 VMEM)
#pragma unroll
  for (int q = 0; q < 4; ++q)
    lds_load16(&As[0][tid * 8 + q * 2048], gA[q]);
#pragma unroll
  for (int ks = 0; ks < 2; ++ks)
#pragma unroll
    for (int j = 0; j < 2; ++j) {
      bgv[ks][j] = *(const float4*)(gBg + ks * 32 + 4 * j);
      buv[ks][j] = *(const float4*)(gBu + ks * 32 + 4 * j);
    }

  for (int k = 0; k < 15; ++k) {
    const int cur = k & 1, nxt = cur ^ 1;
    // issue k+1: A -> As[nxt] (4), B -> regs (8). All stay in flight past BAR.
#pragma unroll
    for (int q = 0; q < 4; ++q)
      lds_load16(&As[nxt][tid * 8 + q * 2048], gA[q] + (k + 1) * 64);
    float4 bgn[2][2], bun[2][2];
#pragma unroll
    for (int ks = 0; ks < 2; ++ks)
#pragma unroll
      for (int j = 0; j < 2; ++j) {
        bgn[ks][j] = *(const float4*)(gBg + (k + 1) * 64 + ks * 32 + 4 * j);
        bun[ks][j] = *(const float4*)(gBu + (k + 1) * 64 + ks * 32 + 4 * j);
      }
    WAIT_VM12;                        // retires iter k-1's 12: As[cur] landed, bv ready
    __builtin_amdgcn_sched_barrier(0);
    BAR();                            // all waves' As[cur] stage complete
    __builtin_amdgcn_s_setprio(1);
#pragma unroll
    for (int ks = 0; ks < 2; ++ks) {
      const int sw = ((ks * 4 + lquad) ^ l7) * 8;
      bf16x8 bg = pack8(bgv[ks][0], bgv[ks][1]);
      bf16x8 bu = pack8(buv[ks][0], buv[ks][1]);
#pragma unroll
      for (int mf = 0; mf < 4; ++mf) {
        bf16x8 af = *(const bf16x8*)&As[cur][(wm + mf * 16 + lcol) * 64 + sw];
        aG[mf] = __builtin_amdgcn_mfma_f32_16x16x32_bf16(af, bg, aG[mf], 0, 0, 0);
        aU[mf] = __builtin_amdgcn_mfma_f32_16x16x32_bf16(af, bu, aU[mf], 0, 0, 0);
      }
    }
    __builtin_amdgcn_s_setprio(0);
#pragma unroll
    for (int ks = 0; ks < 2; ++ks)
#pragma unroll
      for (int j = 0; j < 2; ++j) {
        bgv[ks][j] = bgn[ks][j];
        buv[ks][j] = bun[ks][j];
      }
  }
  // peeled last step (k=15, cur=1)
  WAIT_VM0;
  __builtin_amdgcn_sched_barrier(0);
  BAR();
  __builtin_amdgcn_s_setprio(1);
#pragma unroll
  for (int ks = 0; ks < 2; ++ks) {
    const int sw = ((ks * 4 + lquad) ^ l7) * 8;
    bf16x8 bg = pack8(bgv[ks][0], bgv[ks][1]);
    bf16x8 bu = pack8(buv[ks][0], buv[ks][1]);
#pragma unroll
    for (int mf = 0; mf < 4; ++mf) {
      bf16x8 af = *(const bf16x8*)&As[1][(wm + mf * 16 + lcol) * 64 + sw];
      aG[mf] = __builtin_amdgcn_mfma_f32_16x16x32_bf16(af, bg, aG[mf], 0, 0, 0);
      aU[mf] = __builtin_amdgcn_mfma_f32_16x16x32_bf16(af, bu, aU[mf], 0, 0, 0);
    }
  }
  __builtin_amdgcn_s_setprio(0);
  // epilogue: C/D col=lane&15, row=lquad*4+rr (single tile per block, no sync needed)
#pragma unroll
  for (int mf = 0; mf < 4; ++mf) {
#pragma unroll
    for (int rr = 0; rr < 4; ++rr) {
      const int erow = mt * 128 + wm + mf * 16 + lquad * 4 + rr;
      const float wgt = ew[ebase + erow];
      float g = aG[mf][rr], u = aU[mf][rr];
      float s = g / (1.f + __expf(-g));
      hsc[(size_t)(ebase + erow) * IDIM + n0 + wi + lcol] = (bf16)(s * u * wgt);
    }
  }
}

// ---------------- GEMM2: out[tok,h] += hsc[entry,:] . down[e,h,:] ----------------
// Same v6 pipeline, 8 K-steps. Tile M=128 x 64 h-ch, 4 waves 2m x 2h
// (wave-tile 64x32), 16 MFMA/wave/step. B-frags direct from down (rows
// n0+wh+lcol and +16). atomicAdd epilogue into pre-zeroed out.

__global__ __launch_bounds__(256, 3) void gemm2_kernel(
    const bf16* __restrict__ hsc,    // [E*CAP, I] bf16
    const float* __restrict__ down,  // [E,H,I] fp32
    const int* __restrict__ etk, const int* __restrict__ cntpad,
    float* __restrict__ out) {       // [T,H] fp32, pre-zeroed
  __shared__ __align__(16) bf16 As[2][128 * 64];  // 32 KB
  int e, mt;
  if (!tile_lookup(cntpad, blockIdx.y, e, mt)) return;
  const int n0 = blockIdx.x * 64;
  const int ebase = e * CAP;
  const int tid = threadIdx.x, lane = tid & 63, wid = tid >> 6;
  const int wm = (wid >> 1) * 64, wh = (wid & 1) * 32;
  const int lcol = lane & 15, lquad = lane >> 4;
  const int l7 = lcol & 7;
  const int srow = tid >> 3;
  const int swz = ((tid & 7) ^ (srow & 7)) * 8;
  const size_t rbase = (size_t)(ebase + mt * 128);
  const bf16* gA[4];
#pragma unroll
  for (int q = 0; q < 4; ++q)
    gA[q] = hsc + (rbase + srow + 32 * q) * IDIM + swz;
  const float* gB0 = down + (size_t)e * HDIM * IDIM
                   + (size_t)(n0 + wh + lcol) * IDIM + lquad * 8;
  const float* gB1 = gB0 + (size_t)16 * IDIM;

  f32x4 acc[4][2];
#pragma unroll
  for (int mf = 0; mf < 4; ++mf) {
    acc[mf][0] = f32x4{0.f, 0.f, 0.f, 0.f};
    acc[mf][1] = f32x4{0.f, 0.f, 0.f, 0.f};
  }
  float4 b0v[2][2], b1v[2][2];
#pragma unroll
  for (int q = 0; q < 4; ++q)
    lds_load16(&As[0][tid * 8 + q * 2048], gA[q]);
#pragma unroll
  for (int ks = 0; ks < 2; ++ks)
#pragma unroll
    for (int j = 0; j < 2; ++j) {
      b0v[ks][j] = *(const float4*)(gB0 + ks * 32 + 4 * j);
      b1v[ks][j] = *(const float4*)(gB1 + ks * 32 + 4 * j);
    }

  for (int k = 0; k < 7; ++k) {   // IDIM/64 - 1
    const int cur = k & 1, nxt = cur ^ 1;
#pragma unroll
    for (int q = 0; q < 4; ++q)
      lds_load16(&As[nxt][tid * 8 + q * 2048], gA[q] + (k + 1) * 64);
    float4 b0n[2][2], b1n[2][2];
#pragma unroll
    for (int ks = 0; ks < 2; ++ks)
#pragma unroll
      for (int j = 0; j < 2; ++j) {
        b0n[ks][j] = *(const float4*)(gB0 + (k + 1) * 64 + ks * 32 + 4 * j);
        b1n[ks][j] = *(const float4*)(gB1 + (k + 1) * 64 + ks * 32 + 4 * j);
      }
    WAIT_VM12;
    __builtin_amdgcn_sched_barrier(0);
    BAR();
    __builtin_amdgcn_s_setprio(1);
#pragma unroll
    for (int ks = 0; ks < 2; ++ks) {
      const int sw = ((ks * 4 + lquad) ^ l7) * 8;
      bf16x8 b0 = pack8(b0v[ks][0], b0v[ks][1]);
      bf16x8 b1 = pack8(b1v[ks][0], b1v[ks][1]);
#pragma unroll
      for (int mf = 0; mf < 4; ++mf) {
        bf16x8 af = *(const bf16x8*)&As[cur][(wm + mf * 16 + lcol) * 64 + sw];
        acc[mf][0] = __builtin_amdgcn_mfma_f32_16x16x32_bf16(af, b0, acc[mf][0], 0, 0, 0);
        acc[mf][1] = __builtin_amdgcn_mfma_f32_16x16x32_bf16(af, b1, acc[mf][1], 0, 0, 0);
      }
    }
    __builtin_amdgcn_s_setprio(0);
#pragma unroll
    for (int ks = 0; ks < 2; ++ks)
#pragma unroll
      for (int j = 0; j < 2; ++j) {
        b0v[ks][j] = b0n[ks][j];
        b1v[ks][j] = b1n[ks][j];
      }
  }
  // peeled last step (k=7, cur=1)
  WAIT_VM0;
  __builtin_amdgcn_sched_barrier(0);
  BAR();
  __builtin_amdgcn_s_setprio(1);
#pragma unroll
  for (int ks = 0; ks < 2; ++ks) {
    const int sw = ((ks * 4 + lquad) ^ l7) * 8;
    bf16x8 b0 = pack8(b0v[ks][0], b0v[ks][1]);
    bf16x8 b1 = pack8(b1v[ks][0], b1v[ks][1]);
#pragma unroll
    for (int mf = 0; mf < 4; ++mf) {
      bf16x8 af = *(const bf16x8*)&As[1][(wm + mf * 16 + lcol) * 64 + sw];
      acc[mf][0] = __builtin_amdgcn_mfma_f32_16x16x32_bf16(af, b0, acc[mf][0], 0, 0, 0);
      acc[mf][1] = __builtin_amdgcn_mfma_f32_16x16x32_bf16(af, b1, acc[mf][1], 0, 0, 0);
    }
  }
  __builtin_amdgcn_s_setprio(0);
  // epilogue: atomic scatter-accumulate into out (pad rows guarded)
#pragma unroll
  for (int mf = 0; mf < 4; ++mf) {
#pragma unroll
    for (int rr = 0; rr < 4; ++rr) {
      const int row = mt * 128 + wm + mf * 16 + lquad * 4 + rr;
      const int tk = etk[ebase + row];
      const int tok = tk >> 2;
      if (tok < T_TOK) {
        float* orow = out + (size_t)tok * HDIM + n0 + wh + lcol;
        atomicAdd(orow, acc[mf][0][rr]);
        atomicAdd(orow + 16, acc[mf][1][rr]);
      }
    }
  }
}

// ---------------- launch ----------------

extern "C" void kernel_launch(void* const* d_in, const int* in_sizes, int n_in,
                              void* d_out, int out_size, void* d_ws, size_t ws_size,
                              hipStream_t stream) {
  const float* hid_f  = (const float*)d_in[0];
  const int*   idx    = (const int*)d_in[1];
  const float* tw     = (const float*)d_in[2];
  const float* gup_f  = (const float*)d_in[3];
  const float* down_f = (const float*)d_in[4];
  float* out = (float*)d_out;

  uint8_t* ws = (uint8_t*)d_ws;
  size_t off = 0;
  bf16* hid_b = (bf16*)(ws + off);   off += (size_t)(T_TOK + 1) * HDIM * 2;
  int*  etk   = (int*)(ws + off);    off += (size_t)NEXP * CAP * 4;
  float* ewt  = (float*)(ws + off);  off += (size_t)NEXP * CAP * 4;
  int* cntpad = (int*)(ws + off);    off += 256;
  bf16* hsc   = (bf16*)(ws + off);   // 16 MB

  prep_kernel<<<dim3(CVT_BLOCKS + NEXP), dim3(256), 0, stream>>>(
      hid_f, hid_b, idx, tw, etk, ewt, cntpad, out);
  gemm1_kernel<<<dim3(IDIM / 32, MAXTILES), dim3(256), 0, stream>>>(
      hid_b, gup_f, etk, ewt, cntpad, hsc);
  gemm2_kernel<<<dim3(HDIM / 64, MAXTILES), dim3(256), 0, stream>>>(
      hsc, down_f, etk, cntpad, out);
}